// Round 6
// baseline (436.634 us; speedup 1.0000x reference)
//
#include <hip/hip_runtime.h>
#include <cstdint>

#define DEVI __device__ __forceinline__

typedef short  bfx8 __attribute__((ext_vector_type(8)));
typedef float  fx4  __attribute__((ext_vector_type(4)));
typedef unsigned short u16;
typedef unsigned short usx4 __attribute__((ext_vector_type(4)));
typedef unsigned short usx8 __attribute__((ext_vector_type(8)));

constexpr int Bb = 4, Ss = 2048, Dd = 1024, Hh = 16, DKk = 64;
constexpr int Mtok = Bb * Ss;          // 8192 tokens
constexpr int Kdim = 1024, Ndim = 1024;

// fp32 -> bf16 (RNE)
DEVI u16 f2b(float f) {
  unsigned u = __builtin_bit_cast(unsigned, f);
  unsigned r = u + 0x7fffu + ((u >> 16) & 1u);
  return (u16)(r >> 16);
}

// async global->LDS, 16B per lane. lptr must be the wave-uniform base; HW adds lane*16.
DEVI void lds16(const void* gptr, void* lptr) {
  __builtin_amdgcn_global_load_lds(
      reinterpret_cast<const __attribute__((address_space(1))) unsigned int*>(
          reinterpret_cast<uintptr_t>(gptr)),
      reinterpret_cast<__attribute__((address_space(3))) unsigned int*>(
          reinterpret_cast<uintptr_t>(lptr)),
      16, 0, 0);
}

DEVI fx4 mfma16(bfx8 a, bfx8 b, fx4 c) {
  return __builtin_amdgcn_mfma_f32_16x16x32_bf16(a, b, c, 0, 0, 0);
}

// ---------------------------------------------------------------------------
// fp32 -> bf16 elementwise convert, 8 elems/thread
// ---------------------------------------------------------------------------
__global__ __launch_bounds__(256) void f2bf_kernel(const float* __restrict__ in,
                                                   u16* __restrict__ out, int n8) {
  int i = blockIdx.x * blockDim.x + threadIdx.x;
  if (i < n8) {
    const fx4* p = reinterpret_cast<const fx4*>(in + (size_t)i * 8);
    fx4 a = p[0], b = p[1];
    usx8 o;
#pragma unroll
    for (int j = 0; j < 4; ++j) { o[j] = f2b(a[j]); o[4 + j] = f2b(b[j]); }
    *reinterpret_cast<usx8*>(out + (size_t)i * 8) = o;
  }
}

// batched variant: converts 4 equal-size tensors (the weight matrices) in one
// launch; blockIdx.y selects the tensor.
__global__ __launch_bounds__(256) void f2bf4_kernel(const float* __restrict__ i0,
                                                    const float* __restrict__ i1,
                                                    const float* __restrict__ i2,
                                                    const float* __restrict__ i3,
                                                    u16* __restrict__ o0,
                                                    u16* __restrict__ o1,
                                                    u16* __restrict__ o2,
                                                    u16* __restrict__ o3, int n8) {
  const float* in = blockIdx.y == 0 ? i0 : blockIdx.y == 1 ? i1 : blockIdx.y == 2 ? i2 : i3;
  u16* out = blockIdx.y == 0 ? o0 : blockIdx.y == 1 ? o1 : blockIdx.y == 2 ? o2 : o3;
  int i = blockIdx.x * blockDim.x + threadIdx.x;
  if (i < n8) {
    const fx4* p = reinterpret_cast<const fx4*>(in + (size_t)i * 8);
    fx4 a = p[0], b = p[1];
    usx8 o;
#pragma unroll
    for (int j = 0; j < 4; ++j) { o[j] = f2b(a[j]); o[4 + j] = f2b(b[j]); }
    *reinterpret_cast<usx8*>(out + (size_t)i * 8) = o;
  }
}

// ---------------------------------------------------------------------------
// bt-GEMM: C[M,N] = A[M,K] @ B[N,K]^T + bias, bf16 in, fp32 acc.
// 128x128 tile, BK=32, 256 threads (4 waves 2x2), m97 structure.
// MODE 0: out bf16, head-split [B,H,S,DK], val=(acc+bias)*scale   (Q/K proj)
// MODE 1: out bf16 transposed vt[n][tok] via LDS bounce           (V proj)
// MODE 2: out fp32 [M,N], val=acc+bias                            (final)
// ---------------------------------------------------------------------------
template <int MODE>
__global__ __launch_bounds__(256) void gemm_bt(const u16* __restrict__ A,
                                               const u16* __restrict__ Bw,
                                               const float* __restrict__ bias,
                                               void* __restrict__ outp, float scale) {
  __shared__ u16 As[128 * 32];
  __shared__ u16 Bs[128 * 32];
  __shared__ u16 Ct[MODE == 1 ? 128 * 132 : 1];

  const int tid = threadIdx.x, w = tid >> 6, l = tid & 63;
  const int g = l >> 4, ln = l & 15;
  const int wr = w >> 1, wc = w & 1;
  const int row0 = blockIdx.y * 128, col0 = blockIdx.x * 128;

  fx4 acc[4][4];
#pragma unroll
  for (int i = 0; i < 4; ++i)
#pragma unroll
    for (int j = 0; j < 4; ++j) acc[i][j] = 0.0f;

  const int srow = w * 32 + (l >> 2);   // + i*16
  const int scol = (l & 3) * 8;

  for (int kt = 0; kt < Kdim; kt += 32) {
#pragma unroll
    for (int i = 0; i < 2; ++i) {
      int r = srow + i * 16;
      lds16(A + (size_t)(row0 + r) * Kdim + kt + scol, As + w * 1024 + i * 512);
      lds16(Bw + (size_t)(col0 + r) * Kdim + kt + scol, Bs + w * 1024 + i * 512);
    }
    __syncthreads();
    bfx8 af[4], bf[4];
#pragma unroll
    for (int mf = 0; mf < 4; ++mf)
      af[mf] = *reinterpret_cast<const bfx8*>(As + (wr * 64 + mf * 16 + ln) * 32 + g * 8);
#pragma unroll
    for (int nf = 0; nf < 4; ++nf)
      bf[nf] = *reinterpret_cast<const bfx8*>(Bs + (wc * 64 + nf * 16 + ln) * 32 + g * 8);
#pragma unroll
    for (int mf = 0; mf < 4; ++mf)
#pragma unroll
      for (int nf = 0; nf < 4; ++nf) acc[mf][nf] = mfma16(af[mf], bf[nf], acc[mf][nf]);
    __syncthreads();
  }

  float bcol[4];
#pragma unroll
  for (int nf = 0; nf < 4; ++nf) bcol[nf] = bias[col0 + wc * 64 + nf * 16 + ln];

  if constexpr (MODE == 0) {
    u16* out = (u16*)outp;
#pragma unroll
    for (int mf = 0; mf < 4; ++mf)
#pragma unroll
      for (int i = 0; i < 4; ++i) {
        int r = row0 + wr * 64 + mf * 16 + g * 4 + i;
        int b = r >> 11, s = r & 2047;
#pragma unroll
        for (int nf = 0; nf < 4; ++nf) {
          int c = col0 + wc * 64 + nf * 16 + ln;
          float v = (acc[mf][nf][i] + bcol[nf]) * scale;
          out[(size_t)(b * Hh + (c >> 6)) * Ss * DKk + (size_t)s * DKk + (c & 63)] = f2b(v);
        }
      }
  } else if constexpr (MODE == 2) {
    float* out = (float*)outp;
#pragma unroll
    for (int mf = 0; mf < 4; ++mf)
#pragma unroll
      for (int i = 0; i < 4; ++i) {
        int r = row0 + wr * 64 + mf * 16 + g * 4 + i;
#pragma unroll
        for (int nf = 0; nf < 4; ++nf) {
          int c = col0 + wc * 64 + nf * 16 + ln;
          out[(size_t)r * Ndim + c] = acc[mf][nf][i] + bcol[nf];
        }
      }
  } else {
    // MODE 1: transpose via LDS, store vt[n][tok] (n-major, token contiguous)
#pragma unroll
    for (int mf = 0; mf < 4; ++mf)
#pragma unroll
      for (int i = 0; i < 4; ++i) {
        int rl = wr * 64 + mf * 16 + g * 4 + i;
#pragma unroll
        for (int nf = 0; nf < 4; ++nf)
          Ct[rl * 132 + wc * 64 + nf * 16 + ln] = f2b(acc[mf][nf][i] + bcol[nf]);
      }
    __syncthreads();
    u16* out = (u16*)outp;
    int nloc = tid >> 1;
#pragma unroll
    for (int jj = 0; jj < 8; ++jj) {
      int rl = (tid & 1) * 64 + jj * 8;
      usx8 vv;
#pragma unroll
      for (int e = 0; e < 8; ++e) vv[e] = Ct[(rl + e) * 132 + nloc];
      *reinterpret_cast<usx8*>(out + (size_t)(col0 + nloc) * Mtok + row0 + rl) = vv;
    }
  }
}

// ---------------------------------------------------------------------------
// Flash attention, causal. Block = 128 q rows (4 waves x 32), KV tile = 64.
// qh/kh: [B*H][S][64] bf16 (q pre-scaled by DK^-0.5*log2e). vt: [D][B*S] bf16.
// Swapped QK^T: St = mfma(K, Q) -> row=kv, col=q; softmax in-register;
// P -> padded LDS (b64 packed); PV from XOR-swizzled Vt tile.
// ---------------------------------------------------------------------------
__global__ __launch_bounds__(256) void attn_fwd(const u16* __restrict__ qh,
                                                const u16* __restrict__ kh,
                                                const u16* __restrict__ vt,
                                                u16* __restrict__ ctx) {
  __shared__ u16 Ks[64 * 64];       // [kv][dk ^ 8*(kv&7)]
  __shared__ u16 Vts[64 * 64];      // [dk][kv ^ 8*(dk&7)]
  __shared__ u16 Pl[4][32 * 72];    // per-wave P, padded rows (72)

  const int tid = threadIdx.x, w = tid >> 6, l = tid & 63;
  const int g = l >> 4, ln = l & 15;
  const int qt = blockIdx.x, bh = blockIdx.y;
  const int q0 = qt * 128, qw0 = q0 + w * 32;
  const int b = bh >> 4, h = bh & 15;

  const u16* qhead = qh + (size_t)bh * Ss * DKk;
  const u16* khead = kh + (size_t)bh * Ss * DKk;
  const u16* vhead = vt + (size_t)(h * 64) * Mtok + (size_t)b * Ss;

  bfx8 qf_[2][2];
#pragma unroll
  for (int qf = 0; qf < 2; ++qf)
#pragma unroll
    for (int ks = 0; ks < 2; ++ks)
      qf_[qf][ks] = *reinterpret_cast<const bfx8*>(
          qhead + (size_t)(qw0 + qf * 16 + ln) * 64 + ks * 32 + g * 8);

  float m_run[2] = {-1e30f, -1e30f}, l_run[2] = {0.f, 0.f};
  fx4 cacc[2][4];
#pragma unroll
  for (int qf = 0; qf < 2; ++qf)
#pragma unroll
    for (int df = 0; df < 4; ++df) cacc[qf][df] = 0.0f;

  const int ntiles = qt * 2 + 2;
  for (int t = 0; t < ntiles; ++t) {
    const int kt0 = t * 64;
#pragma unroll
    for (int i = 0; i < 2; ++i) {
      int c = i * 256 + tid;
      int kv = c >> 3, dkb = 8 * ((c & 7) ^ (kv & 7));
      lds16(khead + (size_t)(kt0 + kv) * 64 + dkb, Ks + i * 2048 + w * 512);
      int dk = c >> 3, kvb = 8 * ((c & 7) ^ (dk & 7));
      lds16(vhead + (size_t)dk * Mtok + kt0 + kvb, Vts + i * 2048 + w * 512);
    }
    __syncthreads();

    if (kt0 <= qw0 + 31) {
      fx4 sacc[4][2];
#pragma unroll
      for (int kf = 0; kf < 4; ++kf)
#pragma unroll
        for (int qf = 0; qf < 2; ++qf) sacc[kf][qf] = 0.0f;

#pragma unroll
      for (int ks = 0; ks < 2; ++ks) {
        bfx8 kf_[4];
#pragma unroll
        for (int kf = 0; kf < 4; ++kf)
          kf_[kf] = *reinterpret_cast<const bfx8*>(
              Ks + (kf * 16 + ln) * 64 + ((g * 8 + ks * 32) ^ (8 * (ln & 7))));
#pragma unroll
        for (int kf = 0; kf < 4; ++kf)
#pragma unroll
          for (int qf = 0; qf < 2; ++qf)
            sacc[kf][qf] = mfma16(kf_[kf], qf_[qf][ks], sacc[kf][qf]);
      }

      if (kt0 + 63 > qw0) {  // diagonal tile: causal mask
#pragma unroll
        for (int kf = 0; kf < 4; ++kf)
#pragma unroll
          for (int qf = 0; qf < 2; ++qf)
#pragma unroll
            for (int i = 0; i < 4; ++i) {
              int kvg = kt0 + kf * 16 + g * 4 + i;
              int qg = qw0 + qf * 16 + ln;
              if (kvg > qg) sacc[kf][qf][i] = -1e30f;
            }
      }

      float rfac[2];
#pragma unroll
      for (int qf = 0; qf < 2; ++qf) {
        float pm = -1e30f;
#pragma unroll
        for (int kf = 0; kf < 4; ++kf)
#pragma unroll
          for (int i = 0; i < 4; ++i) pm = fmaxf(pm, sacc[kf][qf][i]);
        pm = fmaxf(pm, __shfl_xor(pm, 16));
        pm = fmaxf(pm, __shfl_xor(pm, 32));
        float mnew = fmaxf(m_run[qf], pm);
        float r = __builtin_amdgcn_exp2f(m_run[qf] - mnew);
        float ps = 0.f;
#pragma unroll
        for (int kf = 0; kf < 4; ++kf)
#pragma unroll
          for (int i = 0; i < 4; ++i) {
            float p = __builtin_amdgcn_exp2f(sacc[kf][qf][i] - mnew);
            sacc[kf][qf][i] = p;
            ps += p;
          }
        l_run[qf] = l_run[qf] * r + ps;
        m_run[qf] = mnew;
        rfac[qf] = r;
      }

      // P -> LDS (packed 4x bf16 = b64 writes)
#pragma unroll
      for (int kf = 0; kf < 4; ++kf)
#pragma unroll
        for (int qf = 0; qf < 2; ++qf) {
          usx4 pw;
#pragma unroll
          for (int i = 0; i < 4; ++i) pw[i] = f2b(sacc[kf][qf][i]);
          *reinterpret_cast<usx4*>(&Pl[w][(qf * 16 + ln) * 72 + kf * 16 + g * 4]) = pw;
        }

      // rescale ctx accumulator
      float rb[2][4];
#pragma unroll
      for (int qf = 0; qf < 2; ++qf)
#pragma unroll
        for (int i = 0; i < 4; ++i) rb[qf][i] = __shfl(rfac[qf], g * 4 + i);
#pragma unroll
      for (int qf = 0; qf < 2; ++qf)
#pragma unroll
        for (int df = 0; df < 4; ++df)
#pragma unroll
          for (int i = 0; i < 4; ++i) cacc[qf][df][i] *= rb[qf][i];

      // PV
#pragma unroll
      for (int ks = 0; ks < 2; ++ks) {
        bfx8 pa[2], vb[4];
#pragma unroll
        for (int qf = 0; qf < 2; ++qf)
          pa[qf] = *reinterpret_cast<const bfx8*>(
              &Pl[w][(qf * 16 + ln) * 72 + ks * 32 + g * 8]);
#pragma unroll
        for (int df = 0; df < 4; ++df)
          vb[df] = *reinterpret_cast<const bfx8*>(
              Vts + (df * 16 + ln) * 64 + ((g * 8 + ks * 32) ^ (8 * (ln & 7))));
#pragma unroll
        for (int qf = 0; qf < 2; ++qf)
#pragma unroll
          for (int df = 0; df < 4; ++df)
            cacc[qf][df] = mfma16(pa[qf], vb[df], cacc[qf][df]);
      }
    }
    __syncthreads();
  }

  // epilogue: normalize and store ctx bf16 [B,S,D]
#pragma unroll
  for (int qf = 0; qf < 2; ++qf) {
    float ls = l_run[qf];
    ls += __shfl_xor(ls, 16);
    ls += __shfl_xor(ls, 32);
    l_run[qf] = ls;
  }
  float linv[2][4];
#pragma unroll
  for (int qf = 0; qf < 2; ++qf)
#pragma unroll
    for (int i = 0; i < 4; ++i) linv[qf][i] = 1.0f / __shfl(l_run[qf], g * 4 + i);

#pragma unroll
  for (int qf = 0; qf < 2; ++qf)
#pragma unroll
    for (int df = 0; df < 4; ++df)
#pragma unroll
      for (int i = 0; i < 4; ++i) {
        int qg = q0 + w * 32 + qf * 16 + g * 4 + i;
        int n = h * 64 + df * 16 + ln;
        ctx[(size_t)(b * Ss + qg) * Dd + n] = f2b(cacc[qf][df][i] * linv[qf][i]);
      }
}

// ---------------------------------------------------------------------------
extern "C" void kernel_launch(void* const* d_in, const int* in_sizes, int n_in,
                              void* d_out, int out_size, void* d_ws, size_t ws_size,
                              hipStream_t stream) {
  // Diagnostic guard: if the workspace is smaller than our 72MB plan, bail out
  // cleanly (d_out stays poisoned -> clean validation failure) instead of
  // writing OOB and potentially killing the container.
  if (ws_size < (size_t)(72u << 20)) return;

  const float* q  = (const float*)d_in[0];
  const float* k  = (const float*)d_in[1];
  const float* v  = (const float*)d_in[2];
  const float* Wq = (const float*)d_in[4];
  const float* bq = (const float*)d_in[5];
  const float* Wk = (const float*)d_in[6];
  const float* bk = (const float*)d_in[7];
  const float* Wv = (const float*)d_in[8];
  const float* bv = (const float*)d_in[9];
  const float* Wo = (const float*)d_in[10];
  const float* bo = (const float*)d_in[11];

  char* ws = (char*)d_ws;
  // layout (bytes): [0,16M) X bf16 / later reused as ctx; [16M,24M) weights bf16;
  // [24M,40M) qh; [40M,56M) kh; [56M,72M) vt.  total 72 MB.
  u16* xb  = (u16*)(ws);
  u16* ctw = (u16*)(ws);                 // reuse X buffer after last X consumer
  u16* wbq = (u16*)(ws + (16u << 20));
  u16* wbk = (u16*)(ws + (18u << 20));
  u16* wbv = (u16*)(ws + (20u << 20));
  u16* wbo = (u16*)(ws + (22u << 20));
  u16* qhw = (u16*)(ws + (24u << 20));
  u16* khw = (u16*)(ws + (40u << 20));
  u16* vtw = (u16*)(ws + (56u << 20));

  const int nX8 = Mtok * Dd / 8;   // 1M chunks
  const int nW8 = Dd * Dd / 8;     // 128K chunks
  dim3 blk(256);
  dim3 gx((nX8 + 255) / 256);
  dim3 gw4((nW8 + 255) / 256, 4);
  dim3 gemmgrid(Ndim / 128, Mtok / 128);

  // all four weight matrices in one launch
  f2bf4_kernel<<<gw4, blk, 0, stream>>>(Wq, Wk, Wv, Wo, wbq, wbk, wbv, wbo, nW8);

  const float qscale = 0.125f * 1.44269504088896340736f;  // DK^-0.5 * log2(e)

  f2bf_kernel<<<gx, blk, 0, stream>>>(q, xb, nX8);
  gemm_bt<0><<<gemmgrid, blk, 0, stream>>>(xb, wbq, bq, qhw, qscale);
  f2bf_kernel<<<gx, blk, 0, stream>>>(k, xb, nX8);
  gemm_bt<0><<<gemmgrid, blk, 0, stream>>>(xb, wbk, bk, khw, 1.0f);
  f2bf_kernel<<<gx, blk, 0, stream>>>(v, xb, nX8);
  gemm_bt<1><<<gemmgrid, blk, 0, stream>>>(xb, wbv, bv, vtw, 1.0f);

  attn_fwd<<<dim3(Ss / 128, Bb * Hh), blk, 0, stream>>>(qhw, khw, vtw, ctw);

  gemm_bt<2><<<gemmgrid, blk, 0, stream>>>(ctw, wbo, bo, d_out, 1.0f);
}